// Round 7
// baseline (137.250 us; speedup 1.0000x reference)
//
#include <hip/hip_runtime.h>
#include <hip/hip_bf16.h>

// EdgeNet fused 2-layer MLP, MI355X (gfx950) — round 7.
//
// out[m][n2] = relu( W2 · relu( W1' · child[m] + b1 ) + b2 ),  W1' = W1 ⊙ parent (folded)
//
// R6 post-mortem: 7.2M bank conflicts (f32 craw frag reads ~8-way), VALU 28%
// (cvt_pk at MFMA time), 800 KB LDS traffic/tile (N-split-8 = every wave reads
// the whole tile), 98 KB LDS -> 1 block/CU.
// R7: (1) stage child as bf16 x-frags (transient-reg stage, cvt once, frag
// reads contiguous = conflict-free, bytes halved); (2) 2x4 MxN wave split
// (wave = 32 rows x 64 cols) cuts LDS amplification 2.5x; (3) LDS 67.5 KB ->
// 2 blocks/CU; non-persistent grid = n_tiles (3125), block desync overlaps
// HBM phases with compute. 2 barriers/block.
//
// MFMA conventions (verified R1..R6, absmax 0.03125):
//   A-frag: lane holds A[row = lane&15][k = 8*(lane>>4)+i], i=0..7
//   B-frag: lane holds B[k = 8*(lane>>4)+i][col = lane&15]
//   C/D  : lane holds C[row = 4*(lane>>4)+reg][col = lane&15]

typedef float f32x4 __attribute__((ext_vector_type(4)));
typedef short bf16x8 __attribute__((ext_vector_type(8)));
typedef unsigned int u32;
typedef u32 u32x4 __attribute__((ext_vector_type(4)));

__device__ __forceinline__ u32 pk2bf(float a, float b) {
    __hip_bfloat162 h2 = __float22bfloat162_rn(make_float2(a, b));
    u32 r;
    __builtin_memcpy(&r, &h2, 4);
    return r;
}

// Pack weights into per-lane MFMA A-fragment order; parent folded into W1.
// halfword[((kt*16 + nt)*64 + lane)*8 + i] = bf16(W'[nt*16 + (lane&15)][kt*32 + 8*(lane>>4) + i])
__global__ __launch_bounds__(256) void pack_w_kernel(
    const float* __restrict__ W1, const float* __restrict__ W2,
    const float* __restrict__ parent, unsigned short* __restrict__ wp)
{
    int t = blockIdx.x * 256 + threadIdx.x;   // 0..16383
    int sel = t >> 13;
    int tt = t & 8191;
    int lane = tt & 63;
    int nt = (tt >> 6) & 15;
    int kt = tt >> 10;
    int n = nt * 16 + (lane & 15);
    int k0 = kt * 32 + 8 * (lane >> 4);
    const float* W = sel ? W2 : W1;
    const float* src = W + n * 256 + k0;
    f32x4 a = *(const f32x4*)src;
    f32x4 b = *(const f32x4*)(src + 4);
    if (sel == 0) {                            // fold parent into W1
        a *= *(const f32x4*)(parent + k0);
        b *= *(const f32x4*)(parent + k0 + 4);
    }
    u32x4 d;
    d.x = pk2bf(a.x, a.y);
    d.y = pk2bf(a.z, a.w);
    d.z = pk2bf(b.x, b.y);
    d.w = pk2bf(b.z, b.w);
    *(u32x4*)(wp + (size_t)t * 8) = d;
}

__global__ __launch_bounds__(512) void fused_mlp(
    const float* __restrict__ child,
    const float* __restrict__ b1, const float* __restrict__ b2,
    const unsigned short* __restrict__ w1p, const unsigned short* __restrict__ w2p,
    float* __restrict__ out, int n_rows)
{
    // x-frags: frag (mf, kt) at halfword (mf*8+kt)*512 + lane*8   (mf<4, kt<8)
    __shared__ __align__(16) unsigned short xf[16384];   // 32 KiB (64 rows bf16)
    __shared__ __align__(16) unsigned short hf[16384];   // 32 KiB h-frags
    __shared__ __align__(16) float bias[512];            // [0..255]=b1, [256..511]=b2

    const int tid = threadIdx.x;
    const int lane = tid & 63;
    const int w = tid >> 6;        // wave 0..7
    const int m16 = lane & 15;
    const int g = lane >> 4;

    if (tid < 256) bias[tid] = b1[tid];
    else           bias[tid] = b2[tid - 256];

    const int tile = blockIdx.x;                // one 64-row tile per block
    const int row0 = tile * 64;

    // ---- stage: wave w loads rows [16*(w>>1),+16), k-half (w&1)*128 -------
    // transient regs only: load f32 -> pk2bf -> ds_write_b128 (lane'==lane).
    {
        const int mfS = w >> 1;
        const int khalf = (w & 1) * 128;
        long row = (long)row0 + mfS * 16 + m16;
        long lim = (long)n_rows - 1;
        if (row > lim) row = lim;               // safety clamp
        const float* cp = child + row * 256 + khalf + 8 * g;
        #pragma unroll
        for (int kt = 0; kt < 4; ++kt) {
            f32x4 c0 = *(const f32x4*)(cp + kt * 32);
            f32x4 c1 = *(const f32x4*)(cp + kt * 32 + 4);
            u32x4 u;
            u.x = pk2bf(c0.x, c0.y);
            u.y = pk2bf(c0.z, c0.w);
            u.z = pk2bf(c1.x, c1.y);
            u.w = pk2bf(c1.z, c1.w);
            const int ktp = (w & 1) * 4 + kt;
            *(u32x4*)&xf[((mfS * 8 + ktp) * 64 + lane) * 8] = u;
        }
    }
    __syncthreads();                            // BAR1: bias + x-frags ready

    // wave (mg, ng): rows [mg*32, +32) (mf = 2mg+mfl), cols [ng*64, +64)
    const int mg = w >> 2;         // 0..1
    const int ng = w & 3;          // 0..3

    // ---- layer 1 ----
    f32x4 acc1[2][4];
    #pragma unroll
    for (int q = 0; q < 4; ++q) {
        f32x4 bv = *(const f32x4*)&bias[(ng * 4 + q) * 16 + 4 * g];
        acc1[0][q] = bv;
        acc1[1][q] = bv;
    }
    #pragma unroll
    for (int kt = 0; kt < 8; ++kt) {
        bf16x8 a0 = *(const bf16x8*)(w1p + (size_t)((kt * 16 + ng * 4 + 0) * 64 + lane) * 8);
        bf16x8 a1 = *(const bf16x8*)(w1p + (size_t)((kt * 16 + ng * 4 + 1) * 64 + lane) * 8);
        bf16x8 a2 = *(const bf16x8*)(w1p + (size_t)((kt * 16 + ng * 4 + 2) * 64 + lane) * 8);
        bf16x8 a3 = *(const bf16x8*)(w1p + (size_t)((kt * 16 + ng * 4 + 3) * 64 + lane) * 8);
        #pragma unroll
        for (int mfl = 0; mfl < 2; ++mfl) {
            bf16x8 bfrag = *(const bf16x8*)&xf[(((mg * 2 + mfl) * 8 + kt) * 64 + lane) * 8];
            acc1[mfl][0] = __builtin_amdgcn_mfma_f32_16x16x32_bf16(a0, bfrag, acc1[mfl][0], 0, 0, 0);
            acc1[mfl][1] = __builtin_amdgcn_mfma_f32_16x16x32_bf16(a1, bfrag, acc1[mfl][1], 0, 0, 0);
            acc1[mfl][2] = __builtin_amdgcn_mfma_f32_16x16x32_bf16(a2, bfrag, acc1[mfl][2], 0, 0, 0);
            acc1[mfl][3] = __builtin_amdgcn_mfma_f32_16x16x32_bf16(a3, bfrag, acc1[mfl][3], 0, 0, 0);
        }
    }

    // ---- relu + pack h -> h-frags -----------------------------------------
    // lane holds h[n = (ng*4+q)*16 + 4g + r][m = (mg*2+mfl)*16 + m16]
    // frag (mf, kt2 = (ng*4+q)>>1), jj = q&1:
    //   lane' = 16*(2jj + (g>>1)) + m16, halfwords 4*(g&1) + r
    #pragma unroll
    for (int mfl = 0; mfl < 2; ++mfl) {
        #pragma unroll
        for (int q = 0; q < 4; ++q) {
            f32x4 v = acc1[mfl][q];
            v.x = fmaxf(v.x, 0.0f); v.y = fmaxf(v.y, 0.0f);
            v.z = fmaxf(v.z, 0.0f); v.w = fmaxf(v.w, 0.0f);
            const int ntg = ng * 4 + q;
            const int kt2 = ntg >> 1;
            const int jj = ntg & 1;
            u32* dst = (u32*)&hf[(((mg * 2 + mfl) * 8 + kt2) * 64 +
                                  16 * (2 * jj + (g >> 1)) + m16) * 8 + 4 * (g & 1)];
            dst[0] = pk2bf(v.x, v.y);
            dst[1] = pk2bf(v.z, v.w);
        }
    }
    __syncthreads();                            // BAR2: h-frags ready

    // ---- layer 2 + epilogue ------------------------------------------------
    f32x4 acc2[2][4];
    #pragma unroll
    for (int q = 0; q < 4; ++q) {
        f32x4 bv = *(const f32x4*)&bias[256 + (ng * 4 + q) * 16 + 4 * g];
        acc2[0][q] = bv;
        acc2[1][q] = bv;
    }
    #pragma unroll
    for (int kt = 0; kt < 8; ++kt) {
        bf16x8 a0 = *(const bf16x8*)(w2p + (size_t)((kt * 16 + ng * 4 + 0) * 64 + lane) * 8);
        bf16x8 a1 = *(const bf16x8*)(w2p + (size_t)((kt * 16 + ng * 4 + 1) * 64 + lane) * 8);
        bf16x8 a2 = *(const bf16x8*)(w2p + (size_t)((kt * 16 + ng * 4 + 2) * 64 + lane) * 8);
        bf16x8 a3 = *(const bf16x8*)(w2p + (size_t)((kt * 16 + ng * 4 + 3) * 64 + lane) * 8);
        #pragma unroll
        for (int mfl = 0; mfl < 2; ++mfl) {
            bf16x8 hfrag = *(const bf16x8*)&hf[(((mg * 2 + mfl) * 8 + kt) * 64 + lane) * 8];
            acc2[mfl][0] = __builtin_amdgcn_mfma_f32_16x16x32_bf16(a0, hfrag, acc2[mfl][0], 0, 0, 0);
            acc2[mfl][1] = __builtin_amdgcn_mfma_f32_16x16x32_bf16(a1, hfrag, acc2[mfl][1], 0, 0, 0);
            acc2[mfl][2] = __builtin_amdgcn_mfma_f32_16x16x32_bf16(a2, hfrag, acc2[mfl][2], 0, 0, 0);
            acc2[mfl][3] = __builtin_amdgcn_mfma_f32_16x16x32_bf16(a3, hfrag, acc2[mfl][3], 0, 0, 0);
        }
    }

    // store: lane holds out[m = (mg*2+mfl)*16 + m16][n2 = (ng*4+q)*16 + 4g + r]
    #pragma unroll
    for (int mfl = 0; mfl < 2; ++mfl) {
        const int m = (mg * 2 + mfl) * 16 + m16;
        if (row0 + m < n_rows) {
            float* orow = out + (size_t)(row0 + m) * 256 + 4 * g;
            #pragma unroll
            for (int q = 0; q < 4; ++q) {
                f32x4 v = acc2[mfl][q];
                v.x = fmaxf(v.x, 0.0f); v.y = fmaxf(v.y, 0.0f);
                v.z = fmaxf(v.z, 0.0f); v.w = fmaxf(v.w, 0.0f);
                *(f32x4*)(orow + (ng * 4 + q) * 16) = v;
            }
        }
    }
}

extern "C" void kernel_launch(void* const* d_in, const int* in_sizes, int n_in,
                              void* d_out, int out_size, void* d_ws, size_t ws_size,
                              hipStream_t stream) {
    const float* parent = (const float*)d_in[0];
    const float* child  = (const float*)d_in[1];
    const float* W1     = (const float*)d_in[2];
    const float* b1     = (const float*)d_in[3];
    const float* W2     = (const float*)d_in[4];
    const float* b2     = (const float*)d_in[5];
    float* out = (float*)d_out;

    unsigned short* wp = (unsigned short*)d_ws;   // [0..65535]=W1' frags, [65536..131071]=W2 frags
    const int n_rows = in_sizes[1] / 256;         // 200000

    pack_w_kernel<<<64, 256, 0, stream>>>(W1, W2, parent, wp);

    const int n_tiles = (n_rows + 63) >> 6;       // 3125 (exact)
    fused_mlp<<<n_tiles, 512, 0, stream>>>(child, b1, b2,
                                           wp, wp + 65536, out, n_rows);
}

// Round 8
// 107.254 us; speedup vs baseline: 1.2797x; 1.2797x over previous
//
#include <hip/hip_runtime.h>
#include <hip/hip_bf16.h>

// EdgeNet fused 2-layer MLP, MI355X (gfx950) — round 8.
//
// out[m][n2] = relu( W2 · relu( W1' · child[m] + b1 ) + b2 ),  W1' = W1 ⊙ parent
//
// R7 post-mortem: VGPR=52 -> per-kt L2 weight-load latency chains exposed; no
// cross-tile prefetch -> stage latency paid serially per block. R8:
//  * WEIGHTS IN REGISTERS: persistent blocks (grid=256, 1/CU); wave w owns
//    col-slice [32w,32w+32) of both layers = 32 bf16x8 frags = 128 VGPRs,
//    loaded ONCE. Zero weight traffic / latency in the tile loop.
//  * launch_bounds(512,2): 2 waves/EU min -> 256-VGPR budget (default ~128
//    caused R4's spills; R5's (512,4) -> 64-reg cap was worse).
//  * Double-buffered bf16 x-frag LDS (2x32K + 32K hf + 2K bias = 98 KiB,
//    1 block/CU): tile t+1's child loads issued into 32 held VGPRs BEFORE
//    tile t's compute; cvt+ds_write after tile t's store. 2 barriers/tile.
//  * Live-reg peak ~212 <= 256 -> no spill (verify: WRITE_SIZE == 200 MB).
//
// MFMA conventions (verified R1..R7, absmax 0.03125):
//   A-frag: lane holds A[row = lane&15][k = 8*(lane>>4)+i], i=0..7
//   B-frag: lane holds B[k = 8*(lane>>4)+i][col = lane&15]
//   C/D  : lane holds C[row = 4*(lane>>4)+reg][col = lane&15]

typedef float f32x4 __attribute__((ext_vector_type(4)));
typedef short bf16x8 __attribute__((ext_vector_type(8)));
typedef unsigned int u32;
typedef u32 u32x4 __attribute__((ext_vector_type(4)));

__device__ __forceinline__ u32 pk2bf(float a, float b) {
    __hip_bfloat162 h2 = __float22bfloat162_rn(make_float2(a, b));
    u32 r;
    __builtin_memcpy(&r, &h2, 4);
    return r;
}

// Pack weights into per-lane MFMA A-fragment order; parent folded into W1.
// halfword[((kt*16 + nt)*64 + lane)*8 + i] = bf16(W'[nt*16 + (lane&15)][kt*32 + 8*(lane>>4) + i])
__global__ __launch_bounds__(256) void pack_w_kernel(
    const float* __restrict__ W1, const float* __restrict__ W2,
    const float* __restrict__ parent, unsigned short* __restrict__ wp)
{
    int t = blockIdx.x * 256 + threadIdx.x;   // 0..16383
    int sel = t >> 13;
    int tt = t & 8191;
    int lane = tt & 63;
    int nt = (tt >> 6) & 15;
    int kt = tt >> 10;
    int n = nt * 16 + (lane & 15);
    int k0 = kt * 32 + 8 * (lane >> 4);
    const float* W = sel ? W2 : W1;
    const float* src = W + n * 256 + k0;
    f32x4 a = *(const f32x4*)src;
    f32x4 b = *(const f32x4*)(src + 4);
    if (sel == 0) {                            // fold parent into W1
        a *= *(const f32x4*)(parent + k0);
        b *= *(const f32x4*)(parent + k0 + 4);
    }
    u32x4 d;
    d.x = pk2bf(a.x, a.y);
    d.y = pk2bf(a.z, a.w);
    d.z = pk2bf(b.x, b.y);
    d.w = pk2bf(b.z, b.w);
    *(u32x4*)(wp + (size_t)t * 8) = d;
}

__global__ __launch_bounds__(512, 2) void fused_mlp(
    const float* __restrict__ child,
    const float* __restrict__ b1, const float* __restrict__ b2,
    const unsigned short* __restrict__ w1p, const unsigned short* __restrict__ w2p,
    float* __restrict__ out, int n_rows)
{
    // x-frags (double-buffered): frag (mf, kt) at halfword (mf*8+kt)*512 + lane*8
    __shared__ __align__(16) unsigned short xf[2][16384];  // 2 x 32 KiB
    __shared__ __align__(16) unsigned short hf[16384];     // 32 KiB h-frags
    __shared__ __align__(16) float bias[512];              // [0..255]=b1, [256..511]=b2

    const int tid = threadIdx.x;
    const int lane = tid & 63;
    const int w = tid >> 6;        // wave 0..7; owns cols [32w, 32w+32) both layers
    const int m16 = lane & 15;
    const int g = lane >> 4;
    const int mfS = w >> 1;        // stage role: rows [16*mfS, +16)
    const int khalf = (w & 1) * 128;

    if (tid < 256) bias[tid] = b1[tid];
    else           bias[tid] = b2[tid - 256];

    // ---- load this wave's weight fragments ONCE (128 VGPRs) ----
    bf16x8 wA1[2][8], wA2[2][8];
    #pragma unroll
    for (int ntl = 0; ntl < 2; ++ntl) {
        #pragma unroll
        for (int kt = 0; kt < 8; ++kt) {
            wA1[ntl][kt] = *(const bf16x8*)(w1p + (size_t)((kt * 16 + 2 * w + ntl) * 64 + lane) * 8);
            wA2[ntl][kt] = *(const bf16x8*)(w2p + (size_t)((kt * 16 + 2 * w + ntl) * 64 + lane) * 8);
        }
    }

    const int n_tiles = (n_rows + 63) >> 6;    // 3125 (200000 = 64*3125)

    // transient-held child rows for the NEXT tile (32 VGPRs)
    f32x4 c[8];
    auto load_rows = [&](int tile) {
        long row = (long)tile * 64 + mfS * 16 + m16;
        long lim = (long)n_rows - 1;
        if (row > lim) row = lim;              // safety clamp
        const float* cp = child + row * 256 + khalf + 8 * g;
        #pragma unroll
        for (int kt = 0; kt < 4; ++kt) {
            c[2 * kt]     = *(const f32x4*)(cp + kt * 32);
            c[2 * kt + 1] = *(const f32x4*)(cp + kt * 32 + 4);
        }
    };
    auto stage = [&](int buf) {                // cvt held regs -> x-frags
        #pragma unroll
        for (int kt = 0; kt < 4; ++kt) {
            u32x4 u;
            u.x = pk2bf(c[2 * kt].x, c[2 * kt].y);
            u.y = pk2bf(c[2 * kt].z, c[2 * kt].w);
            u.z = pk2bf(c[2 * kt + 1].x, c[2 * kt + 1].y);
            u.w = pk2bf(c[2 * kt + 1].z, c[2 * kt + 1].w);
            *(u32x4*)&xf[buf][((mfS * 8 + (w & 1) * 4 + kt) * 64 + lane) * 8] = u;
        }
    };

    // prologue: stage first tile
    load_rows(blockIdx.x);
    stage(0);
    __syncthreads();                           // BAR0: bias + xf[0] ready

    int b = 0;
    for (int tile = blockIdx.x; tile < n_tiles; tile += gridDim.x) {
        const int row0 = tile * 64;
        const int nxt = tile + gridDim.x;
        const bool have_nxt = nxt < n_tiles;   // block-uniform

        // ---- issue next tile's loads NOW: latency hidden under both layers
        if (have_nxt) load_rows(nxt);

        // ---- layer 1: acc1[j][mf] over xf[b] ----
        f32x4 acc1[2][4];
        #pragma unroll
        for (int j = 0; j < 2; ++j) {
            f32x4 bv = *(const f32x4*)&bias[(2 * w + j) * 16 + 4 * g];
            #pragma unroll
            for (int mf = 0; mf < 4; ++mf) acc1[j][mf] = bv;
        }
        #pragma unroll
        for (int kt = 0; kt < 8; ++kt) {
            #pragma unroll
            for (int mf = 0; mf < 4; ++mf) {
                bf16x8 bfrag = *(const bf16x8*)&xf[b][((mf * 8 + kt) * 64 + lane) * 8];
                acc1[0][mf] = __builtin_amdgcn_mfma_f32_16x16x32_bf16(wA1[0][kt], bfrag, acc1[0][mf], 0, 0, 0);
                acc1[1][mf] = __builtin_amdgcn_mfma_f32_16x16x32_bf16(wA1[1][kt], bfrag, acc1[1][mf], 0, 0, 0);
            }
        }

        // ---- relu + pack h -> h-frags (kt2 = w) ----
        // lane holds h[k2 = 32w + 16j + 4g + r][m = mf*16 + m16]
        //   -> frag (mf, w), lane' = 16*(2j + (g>>1)) + m16, halfword 4*(g&1) + r
        #pragma unroll
        for (int j = 0; j < 2; ++j) {
            #pragma unroll
            for (int mf = 0; mf < 4; ++mf) {
                f32x4 v = acc1[j][mf];
                v.x = fmaxf(v.x, 0.0f); v.y = fmaxf(v.y, 0.0f);
                v.z = fmaxf(v.z, 0.0f); v.w = fmaxf(v.w, 0.0f);
                u32* dst = (u32*)&hf[((mf * 8 + w) * 64 + 16 * (2 * j + (g >> 1)) + m16) * 8 + 4 * (g & 1)];
                dst[0] = pk2bf(v.x, v.y);
                dst[1] = pk2bf(v.z, v.w);
            }
        }
        __syncthreads();                       // BAR_A: h-frags ready; xf[b] reads done

        // ---- layer 2 + store ----
        f32x4 acc2[2][4];
        #pragma unroll
        for (int j = 0; j < 2; ++j) {
            f32x4 bv = *(const f32x4*)&bias[256 + (2 * w + j) * 16 + 4 * g];
            #pragma unroll
            for (int mf = 0; mf < 4; ++mf) acc2[j][mf] = bv;
        }
        #pragma unroll
        for (int kt = 0; kt < 8; ++kt) {
            #pragma unroll
            for (int mf = 0; mf < 4; ++mf) {
                bf16x8 hfrag = *(const bf16x8*)&hf[((mf * 8 + kt) * 64 + lane) * 8];
                acc2[0][mf] = __builtin_amdgcn_mfma_f32_16x16x32_bf16(wA2[0][kt], hfrag, acc2[0][mf], 0, 0, 0);
                acc2[1][mf] = __builtin_amdgcn_mfma_f32_16x16x32_bf16(wA2[1][kt], hfrag, acc2[1][mf], 0, 0, 0);
            }
        }

        // store: lane holds out[m = mf*16+m16][n2 = (2w+j)*16 + 4g + r]
        #pragma unroll
        for (int mf = 0; mf < 4; ++mf) {
            if (row0 + mf * 16 < n_rows) {     // wave-uniform
                float* orow = out + (size_t)(row0 + mf * 16 + m16) * 256 + 4 * g;
                #pragma unroll
                for (int j = 0; j < 2; ++j) {
                    f32x4 v = acc2[j][mf];
                    v.x = fmaxf(v.x, 0.0f); v.y = fmaxf(v.y, 0.0f);
                    v.z = fmaxf(v.z, 0.0f); v.w = fmaxf(v.w, 0.0f);
                    *(f32x4*)(orow + (2 * w + j) * 16) = v;
                }
            }
        }

        // ---- cvt+write next tile's x-frags into the other buffer ----
        if (have_nxt) stage(b ^ 1);
        __syncthreads();                       // BAR_B: xf[b^1] ready; hf reads done
        b ^= 1;
    }
}

extern "C" void kernel_launch(void* const* d_in, const int* in_sizes, int n_in,
                              void* d_out, int out_size, void* d_ws, size_t ws_size,
                              hipStream_t stream) {
    const float* parent = (const float*)d_in[0];
    const float* child  = (const float*)d_in[1];
    const float* W1     = (const float*)d_in[2];
    const float* b1     = (const float*)d_in[3];
    const float* W2     = (const float*)d_in[4];
    const float* b2     = (const float*)d_in[5];
    float* out = (float*)d_out;

    unsigned short* wp = (unsigned short*)d_ws;   // [0..65535]=W1' frags, [65536..131071]=W2 frags
    const int n_rows = in_sizes[1] / 256;         // 200000

    pack_w_kernel<<<64, 256, 0, stream>>>(W1, W2, parent, wp);
    fused_mlp<<<256, 512, 0, stream>>>(child, b1, b2,
                                       wp, wp + 65536, out, n_rows);
}